// Round 6
// baseline (1143.679 us; speedup 1.0000x reference)
//
#include <hip/hip_runtime.h>

#define IMG 512
#define CIN 32
#define COUT 32
#define NORI 8
#define HW (IMG*IMG)

#define TS 16

// ---- K1 staging geometry (halo 1) ----
#define W1 18
#define WR1 19
#define CHS1 (W1*WR1)
#define CB1 16

// ---- K2 staging geometry (halo 4) ----
#define HALO 4
#define WIN 24
#define WROW 25
#define CHS2 (WIN*WROW)
#define CB2 16

// tw layout: tw[((r*9 + k)*CIN + c)*COUT + o]
__global__ void build_tw_kernel(const float* __restrict__ weight, float* __restrict__ tw) {
    int idx = blockIdx.x * blockDim.x + threadIdx.x;
    if (idx >= COUT * CIN) return;
    int o = idx / CIN, c = idx % CIN;
    float b[9];
#pragma unroll
    for (int t = 0; t < 9; ++t) b[t] = weight[(o * CIN + c) * 9 + t];

    float w45[9];
    const float cs = 0.70710678f;
#pragma unroll
    for (int i = 0; i < 3; ++i) {
#pragma unroll
        for (int j = 0; j < 3; ++j) {
            float ys = cs * (float)(i - 1) + cs * (float)(j - 1) + 1.0f;
            float xs = -cs * (float)(i - 1) + cs * (float)(j - 1) + 1.0f;
            float y0f = floorf(ys), x0f = floorf(xs);
            float wy = ys - y0f, wx = xs - x0f;
            int iy0 = (int)y0f, ix0 = (int)x0f;
            float a = 0.0f;
#pragma unroll
            for (int dy = 0; dy < 2; ++dy) {
#pragma unroll
                for (int dx = 0; dx < 2; ++dx) {
                    int iy = iy0 + dy, ix = ix0 + dx;
                    float wgt = (dy ? wy : 1.0f - wy) * (dx ? wx : 1.0f - wx);
                    bool valid = (iy >= 0) && (iy < 3) && (ix >= 0) && (ix < 3);
                    int iyc = min(max(iy, 0), 2), ixc = min(max(ix, 0), 2);
                    a += b[iyc * 3 + ixc] * (valid ? wgt : 0.0f);
                }
            }
            w45[i * 3 + j] = a;
        }
    }

#pragma unroll
    for (int r = 0; r < NORI; ++r) {
        const float* src = (r < 4) ? b : w45;
        int rr = r & 3;
#pragma unroll
        for (int i = 0; i < 3; ++i) {
#pragma unroll
            for (int j = 0; j < 3; ++j) {
                int si, sj;
                if (rr == 0) { si = i;     sj = j;     }
                else if (rr == 1) { si = j;     sj = 2 - i; }
                else if (rr == 2) { si = 2 - i; sj = 2 - j; }
                else { si = 2 - j; sj = i;     }
                tw[(((r * 9) + (i * 3 + j)) * CIN + c) * COUT + o] = src[si * 3 + sj];
            }
        }
    }
}

// K1: 3x3 conv 32ch -> 18 offset + 9 sigmoided mask channels, planar om[27][HW]
__global__ __launch_bounds__(256, 4) void offset_mask_kernel(
    const float* __restrict__ x,
    const float* __restrict__ offw, const float* __restrict__ offb,
    const float* __restrict__ mskw, const float* __restrict__ mskb,
    float* __restrict__ om)
{
    __shared__ float L[CB1 * CHS1];

    const int tiles_x = IMG / TS;
    int bid = (int)blockIdx.x;
    bid = (bid % 8) * (1024 / 8) + bid / 8;   // XCD band swizzle (bijective)
    int bx = bid % tiles_x, by = bid / tiles_x;
    int tx = threadIdx.x & 15, ty = threadIdx.x >> 4;
    int X = bx * TS + tx, Y = by * TS + ty;
    int p = Y * IMG + X;
    int y0w = by * TS - 1, x0w = bx * TS - 1;

    float acc[27];
#pragma unroll
    for (int i = 0; i < 18; ++i) acc[i] = offb[i];
#pragma unroll
    for (int i = 0; i < 9; ++i) acc[18 + i] = mskb[i];

    for (int cb = 0; cb < CIN / CB1; ++cb) {
        __syncthreads();
        for (int i = threadIdx.x; i < CB1 * W1 * W1; i += 256) {
            int ch = i / (W1 * W1), cell = i % (W1 * W1);
            int rr = cell / W1, cc = cell % W1;
            int gy = y0w + rr, gx = x0w + cc;
            float v = 0.0f;
            if ((unsigned)gy < (unsigned)IMG && (unsigned)gx < (unsigned)IMG)
                v = x[(cb * CB1 + ch) * HW + gy * IMG + gx];
            L[ch * CHS1 + rr * WR1 + cc] = v;
        }
        __syncthreads();

        for (int ch = 0; ch < CB1; ++ch) {
            int c = cb * CB1 + ch;
            int base = ch * CHS1 + ty * WR1 + tx;
            float v[9];
#pragma unroll
            for (int j = 0; j < 3; ++j) {
                v[j * 3 + 0] = L[base + j * WR1 + 0];
                v[j * 3 + 1] = L[base + j * WR1 + 1];
                v[j * 3 + 2] = L[base + j * WR1 + 2];
            }
            const float* wo = offw + c * 9;   // wave-uniform -> s_load
#pragma unroll
            for (int oc = 0; oc < 18; ++oc)
#pragma unroll
                for (int t = 0; t < 9; ++t)
                    acc[oc] = fmaf(v[t], wo[oc * CIN * 9 + t], acc[oc]);
            const float* wm = mskw + c * 9;
#pragma unroll
            for (int oc = 0; oc < 9; ++oc)
#pragma unroll
                for (int t = 0; t < 9; ++t)
                    acc[18 + oc] = fmaf(v[t], wm[oc * CIN * 9 + t], acc[18 + oc]);
        }
    }

    acc[8] = 0.0f; acc[9] = 0.0f; acc[22] = 0.0f;
#pragma unroll
    for (int oc = 0; oc < 18; ++oc) om[oc * HW + p] = acc[oc];
#pragma unroll
    for (int mk = 0; mk < 9; ++mk)
        om[(18 + mk) * HW + p] = 1.0f / (1.0f + __expf(-acc[18 + mk]));
}

// K2: deformable sampling + per-pixel GEMV + relu.
// Sector loop forces wave-uniform tw addresses -> scalar s_load stream,
// eliminating the 2304 per-lane vector loads of tw that made R5 latency-bound.
__global__ __launch_bounds__(256, 4) void deform_gemv_kernel(
    const float* __restrict__ x,
    const float* __restrict__ om,
    const float* __restrict__ gm,
    const float* __restrict__ tw,
    float* __restrict__ out)
{
    __shared__ float L[CB2 * CHS2];

    const int tiles_x = IMG / TS;
    int bid = (int)blockIdx.x;
    bid = (bid % 8) * (1024 / 8) + bid / 8;
    int bx = bid % tiles_x, by = bid / tiles_x;
    int tx = threadIdx.x & 15, ty = threadIdx.x >> 4;
    int X = bx * TS + tx, Y = by * TS + ty;
    int p = Y * IMG + X;
    int y0w = by * TS - HALO, x0w = bx * TS - HALO;

    int r = 0;
#pragma unroll
    for (int n = 1; n < NORI; ++n) r = (gm[n * HW + p] > 0.5f) ? n : r;

    float oacc[32];
#pragma unroll
    for (int o = 0; o < 32; ++o) oacc[o] = 0.0f;

    for (int cb = 0; cb < CIN / CB2; ++cb) {
        __syncthreads();
        for (int i = threadIdx.x; i < CB2 * WIN * WIN; i += 256) {
            int ch = i / (WIN * WIN), cell = i % (WIN * WIN);
            int rr = cell / WIN, cc = cell % WIN;
            int gy = y0w + rr, gx = x0w + cc;
            float v = 0.0f;
            if ((unsigned)gy < (unsigned)IMG && (unsigned)gx < (unsigned)IMG)
                v = x[(cb * CB2 + ch) * HW + gy * IMG + gx];
            L[ch * CHS2 + rr * WROW + cc] = v;
        }
        __syncthreads();

        for (int k = 0; k < 9; ++k) {
            int ky = k / 3, kx = k - ky * 3;
            float offy = om[(2 * k) * HW + p];
            float offx = om[(2 * k + 1) * HW + p];
            float m    = om[(18 + k) * HW + p];
            float pyf = (float)(Y - 1 + ky) + offy;
            float pxf = (float)(X - 1 + kx) + offx;
            float y0f = floorf(pyf), x0f = floorf(pxf);
            float wy = pyf - y0f, wx = pxf - x0f;
            int iy0 = (int)y0f, ix0 = (int)x0f;
            int iy1 = iy0 + 1, ix1 = ix0 + 1;
            float vy0 = ((unsigned)iy0 < (unsigned)IMG) ? 1.0f : 0.0f;
            float vy1 = ((unsigned)iy1 < (unsigned)IMG) ? 1.0f : 0.0f;
            float vx0 = ((unsigned)ix0 < (unsigned)IMG) ? 1.0f : 0.0f;
            float vx1 = ((unsigned)ix1 < (unsigned)IMG) ? 1.0f : 0.0f;
            int cy0 = min(max(iy0, 0), IMG - 1), cy1 = min(max(iy1, 0), IMG - 1);
            int cx0 = min(max(ix0, 0), IMG - 1), cx1 = min(max(ix1, 0), IMG - 1);
            float w00 = m * (1.0f - wy) * (1.0f - wx) * vy0 * vx0;
            float w01 = m * (1.0f - wy) * wx * vy0 * vx1;
            float w10 = m * wy * (1.0f - wx) * vy1 * vx0;
            float w11 = m * wy * wx * vy1 * vx1;

            int ry0 = cy0 - y0w, rx0 = cx0 - x0w;
            int ry1 = cy1 - y0w, rx1 = cx1 - x0w;
            bool inwin = ((unsigned)ry0 < WIN) && ((unsigned)rx0 < WIN) &&
                         ((unsigned)ry1 < WIN) && ((unsigned)rx1 < WIN);
            bool allin = __all(inwin);
            // per-corner clamped indexing (R3 fix)
            int l00 = ry0 * WROW + rx0, l01 = ry0 * WROW + rx1;
            int l10 = ry1 * WROW + rx0, l11 = ry1 * WROW + rx1;
            int g00 = cy0 * IMG + cx0, g01 = cy0 * IMG + cx1;
            int g10 = cy1 * IMG + cx0, g11 = cy1 * IMG + cx1;

            // sector loop: rs is SGPR -> tw loads are wave-uniform s_loads
            unsigned long long todo = ~0ULL;
            while (todo) {
                int lead = (int)__builtin_ctzll(todo);
                int rs = __builtin_amdgcn_readlane(r, lead);
                bool mine = (r == rs);
                todo &= ~__ballot(mine);
                const float* twk = tw + ((rs * 9 + k) * CIN + cb * CB2) * COUT;
                if (allin) {
                    if (mine) {
                        for (int ch = 0; ch < CB2; ++ch) {
                            int lb = ch * CHS2;
                            float s = fmaf(w00, L[lb + l00], fmaf(w01, L[lb + l01],
                                      fmaf(w10, L[lb + l10], w11 * L[lb + l11])));
                            const float4* t4p = (const float4*)(twk + ch * COUT);
#pragma unroll
                            for (int oq = 0; oq < 8; ++oq) {
                                float4 t4 = t4p[oq];
                                oacc[oq * 4 + 0] = fmaf(s, t4.x, oacc[oq * 4 + 0]);
                                oacc[oq * 4 + 1] = fmaf(s, t4.y, oacc[oq * 4 + 1]);
                                oacc[oq * 4 + 2] = fmaf(s, t4.z, oacc[oq * 4 + 2]);
                                oacc[oq * 4 + 3] = fmaf(s, t4.w, oacc[oq * 4 + 3]);
                            }
                        }
                    }
                } else {
                    if (mine) {
                        for (int ch = 0; ch < CB2; ++ch) {
                            const float* xc = x + (cb * CB2 + ch) * HW;
                            float s = fmaf(w00, xc[g00], fmaf(w01, xc[g01],
                                      fmaf(w10, xc[g10], w11 * xc[g11])));
                            const float4* t4p = (const float4*)(twk + ch * COUT);
#pragma unroll
                            for (int oq = 0; oq < 8; ++oq) {
                                float4 t4 = t4p[oq];
                                oacc[oq * 4 + 0] = fmaf(s, t4.x, oacc[oq * 4 + 0]);
                                oacc[oq * 4 + 1] = fmaf(s, t4.y, oacc[oq * 4 + 1]);
                                oacc[oq * 4 + 2] = fmaf(s, t4.z, oacc[oq * 4 + 2]);
                                oacc[oq * 4 + 3] = fmaf(s, t4.w, oacc[oq * 4 + 3]);
                            }
                        }
                    }
                }
            }
        }
    }

#pragma unroll
    for (int o = 0; o < 32; ++o) out[o * HW + p] = fmaxf(oacc[o], 0.0f);
}

extern "C" void kernel_launch(void* const* d_in, const int* in_sizes, int n_in,
                              void* d_out, int out_size, void* d_ws, size_t ws_size,
                              hipStream_t stream) {
    const float* x      = (const float*)d_in[0];
    const float* weight = (const float*)d_in[1];
    const float* offw   = (const float*)d_in[2];
    const float* offb   = (const float*)d_in[3];
    const float* mskw   = (const float*)d_in[4];
    const float* mskb   = (const float*)d_in[5];
    const float* gm     = (const float*)d_in[6];
    float* out = (float*)d_out;

    float* tw = (float*)d_ws;                       // 294912 B
    float* om = (float*)((char*)d_ws + 294912);     // 27*HW*4 = 28.3 MB

    build_tw_kernel<<<4, 256, 0, stream>>>(weight, tw);

    const int tiles = (IMG / TS) * (IMG / TS); // 1024
    offset_mask_kernel<<<tiles, 256, 0, stream>>>(x, offw, offb, mskw, mskb, om);
    deform_gemv_kernel<<<tiles, 256, 0, stream>>>(x, om, gm, tw, out);
}

// Round 8
// 354.714 us; speedup vs baseline: 3.2242x; 3.2242x over previous
//
#include <hip/hip_runtime.h>

#define IMG 512
#define CIN 32
#define COUT 32
#define NORI 8
#define HW (IMG*IMG)

#define TS 16

// ---- K1 staging geometry (halo 1) ----
#define W1 18
#define WR1 19
#define CHS1 (W1*WR1)
#define CB1 16

// ---- K2 staging geometry (halo 4) ----
#define HALO 4
#define WIN 24
#define WROW 25
#define CHS2 (WIN*WROW)
#define CB2 8

typedef _Float16 h2 __attribute__((ext_vector_type(2)));
typedef __fp16  fp16v2 __attribute__((ext_vector_type(2)));

__device__ __forceinline__ float dot2acc(unsigned int a, unsigned int b, float c) {
#if __has_builtin(__builtin_amdgcn_fdot2)
    return __builtin_amdgcn_fdot2(__builtin_bit_cast(h2, a),
                                  __builtin_bit_cast(h2, b), c, false);
#else
    h2 av = __builtin_bit_cast(h2, a), bv = __builtin_bit_cast(h2, b);
    return fmaf((float)av[0], (float)bv[0], fmaf((float)av[1], (float)bv[1], c));
#endif
}

__device__ __forceinline__ unsigned int packh2(float a, float b) {
#if __has_builtin(__builtin_amdgcn_cvt_pkrtz)
    fp16v2 r = __builtin_amdgcn_cvt_pkrtz(a, b);
    return __builtin_bit_cast(unsigned int, r);
#else
    h2 r; r[0] = (_Float16)a; r[1] = (_Float16)b;
    return __builtin_bit_cast(unsigned int, r);
#endif
}

// tw_h layout (uint = h2 = channel pair): tw_h[((r*9 + k)*(CIN/2) + cp)*COUT + o]
//   = half2( tw[r][k][2cp][o], tw[r][k][2cp+1][o] )
__global__ void build_tw_kernel(const float* __restrict__ weight, unsigned int* __restrict__ tw_h) {
    int idx = blockIdx.x * blockDim.x + threadIdx.x; // 0..511
    if (idx >= COUT * (CIN / 2)) return;
    int o = idx & 31, cp = idx >> 5;

    float bb[2][9], w45[2][9];
    const float cs = 0.70710678f;
#pragma unroll
    for (int h = 0; h < 2; ++h) {
        int c = 2 * cp + h;
#pragma unroll
        for (int t = 0; t < 9; ++t) bb[h][t] = weight[(o * CIN + c) * 9 + t];
#pragma unroll
        for (int i = 0; i < 3; ++i) {
#pragma unroll
            for (int j = 0; j < 3; ++j) {
                float ys = cs * (float)(i - 1) + cs * (float)(j - 1) + 1.0f;
                float xs = -cs * (float)(i - 1) + cs * (float)(j - 1) + 1.0f;
                float y0f = floorf(ys), x0f = floorf(xs);
                float wy = ys - y0f, wx = xs - x0f;
                int iy0 = (int)y0f, ix0 = (int)x0f;
                float a = 0.0f;
#pragma unroll
                for (int dy = 0; dy < 2; ++dy) {
#pragma unroll
                    for (int dx = 0; dx < 2; ++dx) {
                        int iy = iy0 + dy, ix = ix0 + dx;
                        float wgt = (dy ? wy : 1.0f - wy) * (dx ? wx : 1.0f - wx);
                        bool valid = (iy >= 0) && (iy < 3) && (ix >= 0) && (ix < 3);
                        int iyc = min(max(iy, 0), 2), ixc = min(max(ix, 0), 2);
                        a += bb[h][iyc * 3 + ixc] * (valid ? wgt : 0.0f);
                    }
                }
                w45[h][i * 3 + j] = a;
            }
        }
    }

#pragma unroll
    for (int r = 0; r < NORI; ++r) {
        int rr = r & 3;
#pragma unroll
        for (int i = 0; i < 3; ++i) {
#pragma unroll
            for (int j = 0; j < 3; ++j) {
                int si, sj;
                if (rr == 0) { si = i;     sj = j;     }
                else if (rr == 1) { si = j;     sj = 2 - i; }
                else if (rr == 2) { si = 2 - i; sj = 2 - j; }
                else { si = 2 - j; sj = i;     }
                float v0 = (r < 4) ? bb[0][si * 3 + sj] : w45[0][si * 3 + sj];
                float v1 = (r < 4) ? bb[1][si * 3 + sj] : w45[1][si * 3 + sj];
                h2 pk; pk[0] = (_Float16)v0; pk[1] = (_Float16)v1;   // RNE
                tw_h[(((r * 9) + (i * 3 + j)) * (CIN / 2) + cp) * COUT + o] =
                    __builtin_bit_cast(unsigned int, pk);
            }
        }
    }
}

// K1: 3x3 conv 32ch -> 18 offset + 9 sigmoided mask channels, planar om[27][HW]
__global__ __launch_bounds__(256, 4) void offset_mask_kernel(
    const float* __restrict__ x,
    const float* __restrict__ offw, const float* __restrict__ offb,
    const float* __restrict__ mskw, const float* __restrict__ mskb,
    float* __restrict__ om)
{
    __shared__ float L[CB1 * CHS1];

    const int tiles_x = IMG / TS;
    int bid = (int)blockIdx.x;
    bid = (bid % 8) * (1024 / 8) + bid / 8;   // XCD band swizzle (bijective)
    int bx = bid % tiles_x, by = bid / tiles_x;
    int tx = threadIdx.x & 15, ty = threadIdx.x >> 4;
    int X = bx * TS + tx, Y = by * TS + ty;
    int p = Y * IMG + X;
    int y0w = by * TS - 1, x0w = bx * TS - 1;

    float acc[27];
#pragma unroll
    for (int i = 0; i < 18; ++i) acc[i] = offb[i];
#pragma unroll
    for (int i = 0; i < 9; ++i) acc[18 + i] = mskb[i];

    for (int cb = 0; cb < CIN / CB1; ++cb) {
        __syncthreads();
        for (int i = threadIdx.x; i < CB1 * W1 * W1; i += 256) {
            int ch = i / (W1 * W1), cell = i % (W1 * W1);
            int rr = cell / W1, cc = cell % W1;
            int gy = y0w + rr, gx = x0w + cc;
            float v = 0.0f;
            if ((unsigned)gy < (unsigned)IMG && (unsigned)gx < (unsigned)IMG)
                v = x[(cb * CB1 + ch) * HW + gy * IMG + gx];
            L[ch * CHS1 + rr * WR1 + cc] = v;
        }
        __syncthreads();

        for (int ch = 0; ch < CB1; ++ch) {
            int c = cb * CB1 + ch;
            int base = ch * CHS1 + ty * WR1 + tx;
            float v[9];
#pragma unroll
            for (int j = 0; j < 3; ++j) {
                v[j * 3 + 0] = L[base + j * WR1 + 0];
                v[j * 3 + 1] = L[base + j * WR1 + 1];
                v[j * 3 + 2] = L[base + j * WR1 + 2];
            }
            const float* wo = offw + c * 9;   // wave-uniform -> s_load
#pragma unroll
            for (int oc = 0; oc < 18; ++oc)
#pragma unroll
                for (int t = 0; t < 9; ++t)
                    acc[oc] = fmaf(v[t], wo[oc * CIN * 9 + t], acc[oc]);
            const float* wm = mskw + c * 9;
#pragma unroll
            for (int oc = 0; oc < 9; ++oc)
#pragma unroll
                for (int t = 0; t < 9; ++t)
                    acc[18 + oc] = fmaf(v[t], wm[oc * CIN * 9 + t], acc[18 + oc]);
        }
    }

    acc[8] = 0.0f; acc[9] = 0.0f; acc[22] = 0.0f;
#pragma unroll
    for (int oc = 0; oc < 18; ++oc) om[oc * HW + p] = acc[oc];
#pragma unroll
    for (int mk = 0; mk < 9; ++mk)
        om[(18 + mk) * HW + p] = 1.0f / (1.0f + __expf(-acc[18 + mk]));
}

// K2: deformable sampling + per-pixel GEMV (f16 dot2, fp32 accum) + relu.
// R5 control-flow structure (proven spill-free); tw packed f16 channel-pairs
// halves both the tw VMEM stream (2304->1152 dwordx4) and GEMV VALU ops.
__global__ __launch_bounds__(256, 2) void deform_gemv_kernel(
    const float* __restrict__ x,
    const float* __restrict__ om,
    const float* __restrict__ gm,
    const unsigned int* __restrict__ tw_h,
    float* __restrict__ out)
{
    __shared__ float L[CB2 * CHS2];

    const int tiles_x = IMG / TS;
    int bid = (int)blockIdx.x;
    bid = (bid % 8) * (1024 / 8) + bid / 8;
    int bx = bid % tiles_x, by = bid / tiles_x;
    int tx = threadIdx.x & 15, ty = threadIdx.x >> 4;
    int X = bx * TS + tx, Y = by * TS + ty;
    int p = Y * IMG + X;
    int y0w = by * TS - HALO, x0w = bx * TS - HALO;

    int r = 0;
#pragma unroll
    for (int n = 1; n < NORI; ++n) r = (gm[n * HW + p] > 0.5f) ? n : r;

    float oacc[32];
#pragma unroll
    for (int o = 0; o < 32; ++o) oacc[o] = 0.0f;

    for (int cb = 0; cb < CIN / CB2; ++cb) {
        __syncthreads();
        for (int i = threadIdx.x; i < CB2 * WIN * WIN; i += 256) {
            int ch = i / (WIN * WIN), cell = i % (WIN * WIN);
            int rr = cell / WIN, cc = cell % WIN;
            int gy = y0w + rr, gx = x0w + cc;
            float v = 0.0f;
            if ((unsigned)gy < (unsigned)IMG && (unsigned)gx < (unsigned)IMG)
                v = x[(cb * CB2 + ch) * HW + gy * IMG + gx];
            L[ch * CHS2 + rr * WROW + cc] = v;
        }
        __syncthreads();

        for (int k = 0; k < 9; ++k) {   // runtime loop: small body, no arrays
            int ky = k / 3, kx = k - ky * 3;
            float offy = om[(2 * k) * HW + p];
            float offx = om[(2 * k + 1) * HW + p];
            float m    = om[(18 + k) * HW + p];
            float pyf = (float)(Y - 1 + ky) + offy;
            float pxf = (float)(X - 1 + kx) + offx;
            float y0f = floorf(pyf), x0f = floorf(pxf);
            float wy = pyf - y0f, wx = pxf - x0f;
            int iy0 = (int)y0f, ix0 = (int)x0f;
            int iy1 = iy0 + 1, ix1 = ix0 + 1;
            float vy0 = ((unsigned)iy0 < (unsigned)IMG) ? 1.0f : 0.0f;
            float vy1 = ((unsigned)iy1 < (unsigned)IMG) ? 1.0f : 0.0f;
            float vx0 = ((unsigned)ix0 < (unsigned)IMG) ? 1.0f : 0.0f;
            float vx1 = ((unsigned)ix1 < (unsigned)IMG) ? 1.0f : 0.0f;
            int cy0 = min(max(iy0, 0), IMG - 1), cy1 = min(max(iy1, 0), IMG - 1);
            int cx0 = min(max(ix0, 0), IMG - 1), cx1 = min(max(ix1, 0), IMG - 1);
            float w00 = m * (1.0f - wy) * (1.0f - wx) * vy0 * vx0;
            float w01 = m * (1.0f - wy) * wx * vy0 * vx1;
            float w10 = m * wy * (1.0f - wx) * vy1 * vx0;
            float w11 = m * wy * wx * vy1 * vx1;

            int ry0 = cy0 - y0w, rx0 = cx0 - x0w;
            int ry1 = cy1 - y0w, rx1 = cx1 - x0w;
            bool inwin = ((unsigned)ry0 < WIN) && ((unsigned)rx0 < WIN) &&
                         ((unsigned)ry1 < WIN) && ((unsigned)rx1 < WIN);
            // per-corner clamped indexing (R3 fix)
            int l00 = ry0 * WROW + rx0, l01 = ry0 * WROW + rx1;
            int l10 = ry1 * WROW + rx0, l11 = ry1 * WROW + rx1;
            int g00 = cy0 * IMG + cx0, g01 = cy0 * IMG + cx1;
            int g10 = cy1 * IMG + cx0, g11 = cy1 * IMG + cx1;

            // uint4 pointer to this (r,k,cb) slice; 1 uint = 1 channel-pair h2
            const uint4* twp = ((const uint4*)tw_h) +
                               ((unsigned)((r * 9 + k) * (CIN / 2) + cb * (CB2 / 2)) * COUT) / 4;

            if (__all(inwin)) {
                for (int cp = 0; cp < CB2 / 2; ++cp) {
                    int lb0 = (2 * cp) * CHS2, lb1 = lb0 + CHS2;
                    float s0 = fmaf(w00, L[lb0 + l00], fmaf(w01, L[lb0 + l01],
                               fmaf(w10, L[lb0 + l10], w11 * L[lb0 + l11])));
                    float s1 = fmaf(w00, L[lb1 + l00], fmaf(w01, L[lb1 + l01],
                               fmaf(w10, L[lb1 + l10], w11 * L[lb1 + l11])));
                    unsigned int s2 = packh2(s0, s1);
                    const uint4* tp = twp + cp * 8;
#pragma unroll
                    for (int q = 0; q < 8; ++q) {
                        uint4 u = tp[q];
                        oacc[q * 4 + 0] = dot2acc(s2, u.x, oacc[q * 4 + 0]);
                        oacc[q * 4 + 1] = dot2acc(s2, u.y, oacc[q * 4 + 1]);
                        oacc[q * 4 + 2] = dot2acc(s2, u.z, oacc[q * 4 + 2]);
                        oacc[q * 4 + 3] = dot2acc(s2, u.w, oacc[q * 4 + 3]);
                    }
                }
            } else {
                for (int cp = 0; cp < CB2 / 2; ++cp) {
                    const float* xc0 = x + (cb * CB2 + 2 * cp) * HW;
                    const float* xc1 = xc0 + HW;
                    float s0 = fmaf(w00, xc0[g00], fmaf(w01, xc0[g01],
                               fmaf(w10, xc0[g10], w11 * xc0[g11])));
                    float s1 = fmaf(w00, xc1[g00], fmaf(w01, xc1[g01],
                               fmaf(w10, xc1[g10], w11 * xc1[g11])));
                    unsigned int s2 = packh2(s0, s1);
                    const uint4* tp = twp + cp * 8;
#pragma unroll
                    for (int q = 0; q < 8; ++q) {
                        uint4 u = tp[q];
                        oacc[q * 4 + 0] = dot2acc(s2, u.x, oacc[q * 4 + 0]);
                        oacc[q * 4 + 1] = dot2acc(s2, u.y, oacc[q * 4 + 1]);
                        oacc[q * 4 + 2] = dot2acc(s2, u.z, oacc[q * 4 + 2]);
                        oacc[q * 4 + 3] = dot2acc(s2, u.w, oacc[q * 4 + 3]);
                    }
                }
            }
        }
    }

#pragma unroll
    for (int o = 0; o < 32; ++o) out[o * HW + p] = fmaxf(oacc[o], 0.0f);
}

extern "C" void kernel_launch(void* const* d_in, const int* in_sizes, int n_in,
                              void* d_out, int out_size, void* d_ws, size_t ws_size,
                              hipStream_t stream) {
    const float* x      = (const float*)d_in[0];
    const float* weight = (const float*)d_in[1];
    const float* offw   = (const float*)d_in[2];
    const float* offb   = (const float*)d_in[3];
    const float* mskw   = (const float*)d_in[4];
    const float* mskb   = (const float*)d_in[5];
    const float* gm     = (const float*)d_in[6];
    float* out = (float*)d_out;

    unsigned int* tw_h = (unsigned int*)d_ws;       // 8*9*16*32*4 = 147456 B
    float* om = (float*)((char*)d_ws + 294912);     // 27*HW*4 = 28.3 MB

    build_tw_kernel<<<2, 256, 0, stream>>>(weight, tw_h);

    const int tiles = (IMG / TS) * (IMG / TS); // 1024
    offset_mask_kernel<<<tiles, 256, 0, stream>>>(x, offw, offb, mskw, mskb, om);
    deform_gemv_kernel<<<tiles, 256, 0, stream>>>(x, om, gm, tw_h, out);
}

// Round 9
// 291.133 us; speedup vs baseline: 3.9284x; 1.2184x over previous
//
#include <hip/hip_runtime.h>

#define IMG 512
#define CIN 32
#define COUT 32
#define NORI 8
#define HW (IMG*IMG)

#define TS 16

// ---- K1 staging geometry (halo 1) ----
#define W1 18
#define WR1 19
#define CHS1 (W1*WR1)
#define CB1 16

// ---- K2 staging geometry (halo 4) ----
#define HALO 4
#define WIN 24
#define WROW 25
#define CHS2 (WIN*WROW)
#define CB2 8

typedef _Float16 h2 __attribute__((ext_vector_type(2)));
typedef __fp16  fp16v2 __attribute__((ext_vector_type(2)));

__device__ __forceinline__ float dot2acc(unsigned int a, unsigned int b, float c) {
#if __has_builtin(__builtin_amdgcn_fdot2)
    return __builtin_amdgcn_fdot2(__builtin_bit_cast(h2, a),
                                  __builtin_bit_cast(h2, b), c, false);
#else
    h2 av = __builtin_bit_cast(h2, a), bv = __builtin_bit_cast(h2, b);
    return fmaf((float)av[0], (float)bv[0], fmaf((float)av[1], (float)bv[1], c));
#endif
}

__device__ __forceinline__ unsigned int packh2(float a, float b) {
#if __has_builtin(__builtin_amdgcn_cvt_pkrtz)
    fp16v2 r = __builtin_amdgcn_cvt_pkrtz(a, b);
    return __builtin_bit_cast(unsigned int, r);
#else
    h2 r; r[0] = (_Float16)a; r[1] = (_Float16)b;
    return __builtin_bit_cast(unsigned int, r);
#endif
}

#define GEMV8(TP, S2) do {                                             \
    const uint4* _tp = (TP);                                           \
    _Pragma("unroll")                                                  \
    for (int q = 0; q < 8; ++q) {                                      \
        uint4 u = _tp[q];                                              \
        oacc[q * 4 + 0] = dot2acc((S2), u.x, oacc[q * 4 + 0]);         \
        oacc[q * 4 + 1] = dot2acc((S2), u.y, oacc[q * 4 + 1]);         \
        oacc[q * 4 + 2] = dot2acc((S2), u.z, oacc[q * 4 + 2]);         \
        oacc[q * 4 + 3] = dot2acc((S2), u.w, oacc[q * 4 + 3]);         \
    }                                                                  \
} while (0)

// tw_h layout (uint = h2 = channel pair): tw_h[((r*9 + k)*(CIN/2) + cp)*COUT + o]
__global__ void build_tw_kernel(const float* __restrict__ weight, unsigned int* __restrict__ tw_h) {
    int idx = blockIdx.x * blockDim.x + threadIdx.x; // 0..511
    if (idx >= COUT * (CIN / 2)) return;
    int o = idx & 31, cp = idx >> 5;

    float bb[2][9], w45[2][9];
    const float cs = 0.70710678f;
#pragma unroll
    for (int h = 0; h < 2; ++h) {
        int c = 2 * cp + h;
#pragma unroll
        for (int t = 0; t < 9; ++t) bb[h][t] = weight[(o * CIN + c) * 9 + t];
#pragma unroll
        for (int i = 0; i < 3; ++i) {
#pragma unroll
            for (int j = 0; j < 3; ++j) {
                float ys = cs * (float)(i - 1) + cs * (float)(j - 1) + 1.0f;
                float xs = -cs * (float)(i - 1) + cs * (float)(j - 1) + 1.0f;
                float y0f = floorf(ys), x0f = floorf(xs);
                float wy = ys - y0f, wx = xs - x0f;
                int iy0 = (int)y0f, ix0 = (int)x0f;
                float a = 0.0f;
#pragma unroll
                for (int dy = 0; dy < 2; ++dy) {
#pragma unroll
                    for (int dx = 0; dx < 2; ++dx) {
                        int iy = iy0 + dy, ix = ix0 + dx;
                        float wgt = (dy ? wy : 1.0f - wy) * (dx ? wx : 1.0f - wx);
                        bool valid = (iy >= 0) && (iy < 3) && (ix >= 0) && (ix < 3);
                        int iyc = min(max(iy, 0), 2), ixc = min(max(ix, 0), 2);
                        a += bb[h][iyc * 3 + ixc] * (valid ? wgt : 0.0f);
                    }
                }
                w45[h][i * 3 + j] = a;
            }
        }
    }

#pragma unroll
    for (int r = 0; r < NORI; ++r) {
        int rr = r & 3;
#pragma unroll
        for (int i = 0; i < 3; ++i) {
#pragma unroll
            for (int j = 0; j < 3; ++j) {
                int si, sj;
                if (rr == 0) { si = i;     sj = j;     }
                else if (rr == 1) { si = j;     sj = 2 - i; }
                else if (rr == 2) { si = 2 - i; sj = 2 - j; }
                else { si = 2 - j; sj = i;     }
                float v0 = (r < 4) ? bb[0][si * 3 + sj] : w45[0][si * 3 + sj];
                float v1 = (r < 4) ? bb[1][si * 3 + sj] : w45[1][si * 3 + sj];
                h2 pk; pk[0] = (_Float16)v0; pk[1] = (_Float16)v1;   // RNE
                tw_h[(((r * 9) + (i * 3 + j)) * (CIN / 2) + cp) * COUT + o] =
                    __builtin_bit_cast(unsigned int, pk);
            }
        }
    }
}

// K1: 3x3 conv 32ch -> 18 offset + 9 sigmoided mask channels, planar om[27][HW]
__global__ __launch_bounds__(256, 4) void offset_mask_kernel(
    const float* __restrict__ x,
    const float* __restrict__ offw, const float* __restrict__ offb,
    const float* __restrict__ mskw, const float* __restrict__ mskb,
    float* __restrict__ om)
{
    __shared__ float L[CB1 * CHS1];

    const int tiles_x = IMG / TS;
    int bid = (int)blockIdx.x;
    bid = (bid % 8) * (1024 / 8) + bid / 8;   // XCD band swizzle (bijective)
    int bx = bid % tiles_x, by = bid / tiles_x;
    int tx = threadIdx.x & 15, ty = threadIdx.x >> 4;
    int X = bx * TS + tx, Y = by * TS + ty;
    int p = Y * IMG + X;
    int y0w = by * TS - 1, x0w = bx * TS - 1;

    float acc[27];
#pragma unroll
    for (int i = 0; i < 18; ++i) acc[i] = offb[i];
#pragma unroll
    for (int i = 0; i < 9; ++i) acc[18 + i] = mskb[i];

    for (int cb = 0; cb < CIN / CB1; ++cb) {
        __syncthreads();
        for (int i = threadIdx.x; i < CB1 * W1 * W1; i += 256) {
            int ch = i / (W1 * W1), cell = i % (W1 * W1);
            int rr = cell / W1, cc = cell % W1;
            int gy = y0w + rr, gx = x0w + cc;
            float v = 0.0f;
            if ((unsigned)gy < (unsigned)IMG && (unsigned)gx < (unsigned)IMG)
                v = x[(cb * CB1 + ch) * HW + gy * IMG + gx];
            L[ch * CHS1 + rr * WR1 + cc] = v;
        }
        __syncthreads();

        for (int ch = 0; ch < CB1; ++ch) {
            int c = cb * CB1 + ch;
            int base = ch * CHS1 + ty * WR1 + tx;
            float v[9];
#pragma unroll
            for (int j = 0; j < 3; ++j) {
                v[j * 3 + 0] = L[base + j * WR1 + 0];
                v[j * 3 + 1] = L[base + j * WR1 + 1];
                v[j * 3 + 2] = L[base + j * WR1 + 2];
            }
            const float* wo = offw + c * 9;   // wave-uniform -> s_load
#pragma unroll
            for (int oc = 0; oc < 18; ++oc)
#pragma unroll
                for (int t = 0; t < 9; ++t)
                    acc[oc] = fmaf(v[t], wo[oc * CIN * 9 + t], acc[oc]);
            const float* wm = mskw + c * 9;
#pragma unroll
            for (int oc = 0; oc < 9; ++oc)
#pragma unroll
                for (int t = 0; t < 9; ++t)
                    acc[18 + oc] = fmaf(v[t], wm[oc * CIN * 9 + t], acc[18 + oc]);
        }
    }

    acc[8] = 0.0f; acc[9] = 0.0f; acc[22] = 0.0f;
#pragma unroll
    for (int oc = 0; oc < 18; ++oc) om[oc * HW + p] = acc[oc];
#pragma unroll
    for (int mk = 0; mk < 9; ++mk)
        om[(18 + mk) * HW + p] = 1.0f / (1.0f + __expf(-acc[18 + mk]));
}

// K2: deformable sampling + per-pixel GEMV (f16 dot2, fp32 accum) + relu.
// New vs R8: (1) wave-uniform-sector branch -> tw loads scalarize to s_load;
// (2) fast path uses UNCLAMPED in-window corner coords with static
// +1/+WROW offsets (ds_read2_b32; safe because window is zero-filled and
// out-of-image corners have weight 0).
__global__ __launch_bounds__(256, 2) void deform_gemv_kernel(
    const float* __restrict__ x,
    const float* __restrict__ om,
    const float* __restrict__ gm,
    const unsigned int* __restrict__ tw_h,
    float* __restrict__ out)
{
    __shared__ float L[CB2 * CHS2];

    const int tiles_x = IMG / TS;
    int bid = (int)blockIdx.x;
    bid = (bid % 8) * (1024 / 8) + bid / 8;
    int bx = bid % tiles_x, by = bid / tiles_x;
    int tx = threadIdx.x & 15, ty = threadIdx.x >> 4;
    int X = bx * TS + tx, Y = by * TS + ty;
    int p = Y * IMG + X;
    int y0w = by * TS - HALO, x0w = bx * TS - HALO;

    int r = 0;
#pragma unroll
    for (int n = 1; n < NORI; ++n) r = (gm[n * HW + p] > 0.5f) ? n : r;
    int rfl = __builtin_amdgcn_readfirstlane(r);
    bool runi = __all(r == rfl);

    float oacc[32];
#pragma unroll
    for (int o = 0; o < 32; ++o) oacc[o] = 0.0f;

    for (int cb = 0; cb < CIN / CB2; ++cb) {
        __syncthreads();
        for (int i = threadIdx.x; i < CB2 * WIN * WIN; i += 256) {
            int ch = i / (WIN * WIN), cell = i % (WIN * WIN);
            int rr = cell / WIN, cc = cell % WIN;
            int gy = y0w + rr, gx = x0w + cc;
            float v = 0.0f;
            if ((unsigned)gy < (unsigned)IMG && (unsigned)gx < (unsigned)IMG)
                v = x[(cb * CB2 + ch) * HW + gy * IMG + gx];
            L[ch * CHS2 + rr * WROW + cc] = v;
        }
        __syncthreads();

        for (int k = 0; k < 9; ++k) {   // runtime loop: small body, no arrays
            int ky = k / 3, kx = k - ky * 3;
            float offy = om[(2 * k) * HW + p];
            float offx = om[(2 * k + 1) * HW + p];
            float m    = om[(18 + k) * HW + p];
            float pyf = (float)(Y - 1 + ky) + offy;
            float pxf = (float)(X - 1 + kx) + offx;
            float y0f = floorf(pyf), x0f = floorf(pxf);
            float wy = pyf - y0f, wx = pxf - x0f;
            int iy0 = (int)y0f, ix0 = (int)x0f;
            int iy1 = iy0 + 1, ix1 = ix0 + 1;
            float vy0 = ((unsigned)iy0 < (unsigned)IMG) ? 1.0f : 0.0f;
            float vy1 = ((unsigned)iy1 < (unsigned)IMG) ? 1.0f : 0.0f;
            float vx0 = ((unsigned)ix0 < (unsigned)IMG) ? 1.0f : 0.0f;
            float vx1 = ((unsigned)ix1 < (unsigned)IMG) ? 1.0f : 0.0f;
            float w00 = m * (1.0f - wy) * (1.0f - wx) * vy0 * vx0;
            float w01 = m * (1.0f - wy) * wx * vy0 * vx1;
            float w10 = m * wy * (1.0f - wx) * vy1 * vx0;
            float w11 = m * wy * wx * vy1 * vx1;

            // unclamped window coords: if the whole 2x2 quad lies in the
            // window, LDS holds the zero-padded image there and OOB corners
            // have weight 0 -> static-offset quad read is exact.
            int ryu = iy0 - y0w, rxu = ix0 - x0w;
            bool fast = ((unsigned)ryu < (WIN - 1)) && ((unsigned)rxu < (WIN - 1));
            int lq = ryu * WROW + rxu;

            const unsigned int twoff = (unsigned)((9 + k) * (CIN / 2) + cb * (CB2 / 2)) * COUT; // dummy to keep shape
            (void)twoff;

            if (__all(fast)) {
                if (runi) {
                    const uint4* tpU = (const uint4*)(tw_h +
                        (unsigned)((rfl * 9 + k) * (CIN / 2) + cb * (CB2 / 2)) * COUT);
                    for (int cp = 0; cp < CB2 / 2; ++cp) {
                        int lb0 = (2 * cp) * CHS2 + lq, lb1 = lb0 + CHS2;
                        float s0 = fmaf(w00, L[lb0], fmaf(w01, L[lb0 + 1],
                                   fmaf(w10, L[lb0 + WROW], w11 * L[lb0 + WROW + 1])));
                        float s1 = fmaf(w00, L[lb1], fmaf(w01, L[lb1 + 1],
                                   fmaf(w10, L[lb1 + WROW], w11 * L[lb1 + WROW + 1])));
                        unsigned int s2 = packh2(s0, s1);
                        GEMV8(tpU + cp * 8, s2);
                    }
                } else {
                    const uint4* tpL = (const uint4*)(tw_h +
                        (unsigned)((r * 9 + k) * (CIN / 2) + cb * (CB2 / 2)) * COUT);
                    for (int cp = 0; cp < CB2 / 2; ++cp) {
                        int lb0 = (2 * cp) * CHS2 + lq, lb1 = lb0 + CHS2;
                        float s0 = fmaf(w00, L[lb0], fmaf(w01, L[lb0 + 1],
                                   fmaf(w10, L[lb0 + WROW], w11 * L[lb0 + WROW + 1])));
                        float s1 = fmaf(w00, L[lb1], fmaf(w01, L[lb1 + 1],
                                   fmaf(w10, L[lb1 + WROW], w11 * L[lb1 + WROW + 1])));
                        unsigned int s2 = packh2(s0, s1);
                        GEMV8(tpL + cp * 8, s2);
                    }
                }
            } else {
                // slow path (rare, |offset| >= ~3): exact global reads, clamped
                int cy0 = min(max(iy0, 0), IMG - 1), cy1 = min(max(iy1, 0), IMG - 1);
                int cx0 = min(max(ix0, 0), IMG - 1), cx1 = min(max(ix1, 0), IMG - 1);
                int g00 = cy0 * IMG + cx0, g01 = cy0 * IMG + cx1;
                int g10 = cy1 * IMG + cx0, g11 = cy1 * IMG + cx1;
                const uint4* tpL = (const uint4*)(tw_h +
                    (unsigned)((r * 9 + k) * (CIN / 2) + cb * (CB2 / 2)) * COUT);
                for (int cp = 0; cp < CB2 / 2; ++cp) {
                    const float* xc0 = x + (cb * CB2 + 2 * cp) * HW;
                    const float* xc1 = xc0 + HW;
                    float s0 = fmaf(w00, xc0[g00], fmaf(w01, xc0[g01],
                               fmaf(w10, xc0[g10], w11 * xc0[g11])));
                    float s1 = fmaf(w00, xc1[g00], fmaf(w01, xc1[g01],
                               fmaf(w10, xc1[g10], w11 * xc1[g11])));
                    unsigned int s2 = packh2(s0, s1);
                    GEMV8(tpL + cp * 8, s2);
                }
            }
        }
    }

#pragma unroll
    for (int o = 0; o < 32; ++o) out[o * HW + p] = fmaxf(oacc[o], 0.0f);
}

extern "C" void kernel_launch(void* const* d_in, const int* in_sizes, int n_in,
                              void* d_out, int out_size, void* d_ws, size_t ws_size,
                              hipStream_t stream) {
    const float* x      = (const float*)d_in[0];
    const float* weight = (const float*)d_in[1];
    const float* offw   = (const float*)d_in[2];
    const float* offb   = (const float*)d_in[3];
    const float* mskw   = (const float*)d_in[4];
    const float* mskb   = (const float*)d_in[5];
    const float* gm     = (const float*)d_in[6];
    float* out = (float*)d_out;

    unsigned int* tw_h = (unsigned int*)d_ws;       // 147456 B
    float* om = (float*)((char*)d_ws + 294912);     // 27*HW*4 = 28.3 MB

    build_tw_kernel<<<2, 256, 0, stream>>>(weight, tw_h);

    const int tiles = (IMG / TS) * (IMG / TS); // 1024
    offset_mask_kernel<<<tiles, 256, 0, stream>>>(x, offw, offb, mskw, mskb, om);
    deform_gemv_kernel<<<tiles, 256, 0, stream>>>(x, om, gm, tw_h, out);
}

// Round 10
// 205.559 us; speedup vs baseline: 5.5638x; 1.4163x over previous
//
#include <hip/hip_runtime.h>

#define IMG 512
#define CIN 32
#define COUT 32
#define NORI 8
#define HW (IMG*IMG)

#define TS 16

// ---- K1 staging geometry (halo 1), f16 channel-pair cells ----
#define W1 18
#define WR1 19
#define CHS1 (W1*WR1)      // 342 uints per channel-pair
// ---- K2 staging geometry (halo 4) ----
#define HALO 4
#define WIN 24
#define WROW 25
#define CHS2 (WIN*WROW)
#define CB2 8

typedef _Float16 h2 __attribute__((ext_vector_type(2)));
typedef __fp16  fp16v2 __attribute__((ext_vector_type(2)));

__device__ __forceinline__ float dot2acc(unsigned int a, unsigned int b, float c) {
#if __has_builtin(__builtin_amdgcn_fdot2)
    return __builtin_amdgcn_fdot2(__builtin_bit_cast(h2, a),
                                  __builtin_bit_cast(h2, b), c, false);
#else
    h2 av = __builtin_bit_cast(h2, a), bv = __builtin_bit_cast(h2, b);
    return fmaf((float)av[0], (float)bv[0], fmaf((float)av[1], (float)bv[1], c));
#endif
}

__device__ __forceinline__ unsigned int packh2(float a, float b) {
#if __has_builtin(__builtin_amdgcn_cvt_pkrtz)
    fp16v2 r = __builtin_amdgcn_cvt_pkrtz(a, b);
    return __builtin_bit_cast(unsigned int, r);
#else
    h2 r; r[0] = (_Float16)a; r[1] = (_Float16)b;
    return __builtin_bit_cast(unsigned int, r);
#endif
}

#define GEMV8(TP, S2) do {                                             \
    const uint4* _tp = (TP);                                           \
    _Pragma("unroll")                                                  \
    for (int q = 0; q < 8; ++q) {                                      \
        uint4 u = _tp[q];                                              \
        oacc[q * 4 + 0] = dot2acc((S2), u.x, oacc[q * 4 + 0]);         \
        oacc[q * 4 + 1] = dot2acc((S2), u.y, oacc[q * 4 + 1]);         \
        oacc[q * 4 + 2] = dot2acc((S2), u.z, oacc[q * 4 + 2]);         \
        oacc[q * 4 + 3] = dot2acc((S2), u.w, oacc[q * 4 + 3]);         \
    }                                                                  \
} while (0)

// tw_h layout (uint = h2 = channel pair): tw_h[((r*9 + k)*(CIN/2) + cp)*COUT + o]
__global__ void build_tw_kernel(const float* __restrict__ weight, unsigned int* __restrict__ tw_h) {
    int idx = blockIdx.x * blockDim.x + threadIdx.x; // 0..511
    if (idx >= COUT * (CIN / 2)) return;
    int o = idx & 31, cp = idx >> 5;

    float bb[2][9], w45[2][9];
    const float cs = 0.70710678f;
#pragma unroll
    for (int h = 0; h < 2; ++h) {
        int c = 2 * cp + h;
#pragma unroll
        for (int t = 0; t < 9; ++t) bb[h][t] = weight[(o * CIN + c) * 9 + t];
#pragma unroll
        for (int i = 0; i < 3; ++i) {
#pragma unroll
            for (int j = 0; j < 3; ++j) {
                float ys = cs * (float)(i - 1) + cs * (float)(j - 1) + 1.0f;
                float xs = -cs * (float)(i - 1) + cs * (float)(j - 1) + 1.0f;
                float y0f = floorf(ys), x0f = floorf(xs);
                float wy = ys - y0f, wx = xs - x0f;
                int iy0 = (int)y0f, ix0 = (int)x0f;
                float a = 0.0f;
#pragma unroll
                for (int dy = 0; dy < 2; ++dy) {
#pragma unroll
                    for (int dx = 0; dx < 2; ++dx) {
                        int iy = iy0 + dy, ix = ix0 + dx;
                        float wgt = (dy ? wy : 1.0f - wy) * (dx ? wx : 1.0f - wx);
                        bool valid = (iy >= 0) && (iy < 3) && (ix >= 0) && (ix < 3);
                        int iyc = min(max(iy, 0), 2), ixc = min(max(ix, 0), 2);
                        a += bb[h][iyc * 3 + ixc] * (valid ? wgt : 0.0f);
                    }
                }
                w45[h][i * 3 + j] = a;
            }
        }
    }

#pragma unroll
    for (int r = 0; r < NORI; ++r) {
        int rr = r & 3;
#pragma unroll
        for (int i = 0; i < 3; ++i) {
#pragma unroll
            for (int j = 0; j < 3; ++j) {
                int si, sj;
                if (rr == 0) { si = i;     sj = j;     }
                else if (rr == 1) { si = j;     sj = 2 - i; }
                else if (rr == 2) { si = 2 - i; sj = 2 - j; }
                else { si = 2 - j; sj = i;     }
                float v0 = (r < 4) ? bb[0][si * 3 + sj] : w45[0][si * 3 + sj];
                float v1 = (r < 4) ? bb[1][si * 3 + sj] : w45[1][si * 3 + sj];
                h2 pk; pk[0] = (_Float16)v0; pk[1] = (_Float16)v1;   // RNE
                tw_h[(((r * 9) + (i * 3 + j)) * (CIN / 2) + cp) * COUT + o] =
                    __builtin_bit_cast(unsigned int, pk);
            }
        }
    }
}

// Pack offset+mask conv weights as f16 channel-pairs:
// owm[(cp*27 + oc)*9 + t] = h2( w[oc][2cp][t], w[oc][2cp+1][t] ), oc<18 -> offw, else mskw
__global__ void pack_owm_kernel(const float* __restrict__ offw, const float* __restrict__ mskw,
                                unsigned int* __restrict__ owm) {
    int idx = blockIdx.x * blockDim.x + threadIdx.x;
    if (idx >= 27 * (CIN / 2)) return;
    int oc = idx % 27, cp = idx / 27;
    const float* src = (oc < 18) ? (offw + oc * CIN * 9) : (mskw + (oc - 18) * CIN * 9);
#pragma unroll
    for (int t = 0; t < 9; ++t) {
        float a = src[(2 * cp) * 9 + t];
        float b = src[(2 * cp + 1) * 9 + t];
        h2 pk; pk[0] = (_Float16)a; pk[1] = (_Float16)b;   // RNE
        owm[(cp * 27 + oc) * 9 + t] = __builtin_bit_cast(unsigned int, pk);
    }
}

// K1: 3x3 conv 32ch -> 18 offset + 9 sigmoided mask channels, planar om[27][HW].
// f16 dot2 version: x staged as f16 channel-pairs, weights pre-packed (owm) and
// streamed via wave-uniform s_load (halves the 31KB/wave scalar stream that
// made the fp32 version SMEM-bound).
__global__ __launch_bounds__(256, 4) void offset_mask_kernel(
    const float* __restrict__ x,
    const unsigned int* __restrict__ owm,
    const float* __restrict__ offb, const float* __restrict__ mskb,
    float* __restrict__ om)
{
    __shared__ unsigned int Lp[8 * CHS1];   // 8 channel-pairs of f16x2 cells

    const int tiles_x = IMG / TS;
    int bid = (int)blockIdx.x;
    bid = (bid % 8) * (1024 / 8) + bid / 8;   // XCD band swizzle (bijective)
    int bx = bid % tiles_x, by = bid / tiles_x;
    int tx = threadIdx.x & 15, ty = threadIdx.x >> 4;
    int X = bx * TS + tx, Y = by * TS + ty;
    int p = Y * IMG + X;
    int y0w = by * TS - 1, x0w = bx * TS - 1;

    float acc[27];
#pragma unroll
    for (int i = 0; i < 18; ++i) acc[i] = offb[i];
#pragma unroll
    for (int i = 0; i < 9; ++i) acc[18 + i] = mskb[i];

    for (int pb = 0; pb < 2; ++pb) {          // pair-blocks: cp 0..7, 8..15
        __syncthreads();
        for (int i = threadIdx.x; i < 8 * (W1 * W1); i += 256) {
            int pr = i / (W1 * W1), cell = i % (W1 * W1);
            int rr = cell / W1, cc = cell % W1;
            int gy = y0w + rr, gx = x0w + cc;
            float a = 0.0f, b = 0.0f;
            if ((unsigned)gy < (unsigned)IMG && (unsigned)gx < (unsigned)IMG) {
                const float* x0 = x + ((pb * 8 + pr) * 2) * HW + gy * IMG + gx;
                a = x0[0]; b = x0[HW];
            }
            Lp[pr * CHS1 + rr * WR1 + cc] = packh2(a, b);
        }
        __syncthreads();

        for (int pr = 0; pr < 8; ++pr) {
            int cp = pb * 8 + pr;
            int base = pr * CHS1 + ty * WR1 + tx;
            unsigned int v2[9];
#pragma unroll
            for (int j = 0; j < 3; ++j) {
                v2[j * 3 + 0] = Lp[base + j * WR1 + 0];
                v2[j * 3 + 1] = Lp[base + j * WR1 + 1];
                v2[j * 3 + 2] = Lp[base + j * WR1 + 2];
            }
            const unsigned int* wp = owm + cp * 27 * 9;   // wave-uniform -> s_load
#pragma unroll
            for (int oc = 0; oc < 27; ++oc)
#pragma unroll
                for (int t = 0; t < 9; ++t)
                    acc[oc] = dot2acc(v2[t], wp[oc * 9 + t], acc[oc]);
        }
    }

    acc[8] = 0.0f; acc[9] = 0.0f; acc[22] = 0.0f;
#pragma unroll
    for (int oc = 0; oc < 18; ++oc) om[oc * HW + p] = acc[oc];
#pragma unroll
    for (int mk = 0; mk < 9; ++mk)
        om[(18 + mk) * HW + p] = 1.0f / (1.0f + __expf(-acc[18 + mk]));
}

// K2: deformable sampling + per-pixel GEMV (f16 dot2, fp32 accum) + relu.
// Identical to R9 (162 us, verified): wave-uniform-sector s_load branch +
// unclamped in-window static-offset quad reads.
__global__ __launch_bounds__(256, 2) void deform_gemv_kernel(
    const float* __restrict__ x,
    const float* __restrict__ om,
    const float* __restrict__ gm,
    const unsigned int* __restrict__ tw_h,
    float* __restrict__ out)
{
    __shared__ float L[CB2 * CHS2];

    const int tiles_x = IMG / TS;
    int bid = (int)blockIdx.x;
    bid = (bid % 8) * (1024 / 8) + bid / 8;
    int bx = bid % tiles_x, by = bid / tiles_x;
    int tx = threadIdx.x & 15, ty = threadIdx.x >> 4;
    int X = bx * TS + tx, Y = by * TS + ty;
    int p = Y * IMG + X;
    int y0w = by * TS - HALO, x0w = bx * TS - HALO;

    int r = 0;
#pragma unroll
    for (int n = 1; n < NORI; ++n) r = (gm[n * HW + p] > 0.5f) ? n : r;
    int rfl = __builtin_amdgcn_readfirstlane(r);
    bool runi = __all(r == rfl);

    float oacc[32];
#pragma unroll
    for (int o = 0; o < 32; ++o) oacc[o] = 0.0f;

    for (int cb = 0; cb < CIN / CB2; ++cb) {
        __syncthreads();
        for (int i = threadIdx.x; i < CB2 * WIN * WIN; i += 256) {
            int ch = i / (WIN * WIN), cell = i % (WIN * WIN);
            int rr = cell / WIN, cc = cell % WIN;
            int gy = y0w + rr, gx = x0w + cc;
            float v = 0.0f;
            if ((unsigned)gy < (unsigned)IMG && (unsigned)gx < (unsigned)IMG)
                v = x[(cb * CB2 + ch) * HW + gy * IMG + gx];
            L[ch * CHS2 + rr * WROW + cc] = v;
        }
        __syncthreads();

        for (int k = 0; k < 9; ++k) {   // runtime loop: small body, no arrays
            int ky = k / 3, kx = k - ky * 3;
            float offy = om[(2 * k) * HW + p];
            float offx = om[(2 * k + 1) * HW + p];
            float m    = om[(18 + k) * HW + p];
            float pyf = (float)(Y - 1 + ky) + offy;
            float pxf = (float)(X - 1 + kx) + offx;
            float y0f = floorf(pyf), x0f = floorf(pxf);
            float wy = pyf - y0f, wx = pxf - x0f;
            int iy0 = (int)y0f, ix0 = (int)x0f;
            int iy1 = iy0 + 1, ix1 = ix0 + 1;
            float vy0 = ((unsigned)iy0 < (unsigned)IMG) ? 1.0f : 0.0f;
            float vy1 = ((unsigned)iy1 < (unsigned)IMG) ? 1.0f : 0.0f;
            float vx0 = ((unsigned)ix0 < (unsigned)IMG) ? 1.0f : 0.0f;
            float vx1 = ((unsigned)ix1 < (unsigned)IMG) ? 1.0f : 0.0f;
            float w00 = m * (1.0f - wy) * (1.0f - wx) * vy0 * vx0;
            float w01 = m * (1.0f - wy) * wx * vy0 * vx1;
            float w10 = m * wy * (1.0f - wx) * vy1 * vx0;
            float w11 = m * wy * wx * vy1 * vx1;

            // unclamped window coords: whole 2x2 quad in window -> zero-padded
            // LDS + weight-0 OOB corners make static-offset reads exact.
            int ryu = iy0 - y0w, rxu = ix0 - x0w;
            bool fast = ((unsigned)ryu < (WIN - 1)) && ((unsigned)rxu < (WIN - 1));
            int lq = ryu * WROW + rxu;

            if (__all(fast)) {
                if (runi) {
                    const uint4* tpU = (const uint4*)(tw_h +
                        (unsigned)((rfl * 9 + k) * (CIN / 2) + cb * (CB2 / 2)) * COUT);
                    for (int cp = 0; cp < CB2 / 2; ++cp) {
                        int lb0 = (2 * cp) * CHS2 + lq, lb1 = lb0 + CHS2;
                        float s0 = fmaf(w00, L[lb0], fmaf(w01, L[lb0 + 1],
                                   fmaf(w10, L[lb0 + WROW], w11 * L[lb0 + WROW + 1])));
                        float s1 = fmaf(w00, L[lb1], fmaf(w01, L[lb1 + 1],
                                   fmaf(w10, L[lb1 + WROW], w11 * L[lb1 + WROW + 1])));
                        unsigned int s2 = packh2(s0, s1);
                        GEMV8(tpU + cp * 8, s2);
                    }
                } else {
                    const uint4* tpL = (const uint4*)(tw_h +
                        (unsigned)((r * 9 + k) * (CIN / 2) + cb * (CB2 / 2)) * COUT);
                    for (int cp = 0; cp < CB2 / 2; ++cp) {
                        int lb0 = (2 * cp) * CHS2 + lq, lb1 = lb0 + CHS2;
                        float s0 = fmaf(w00, L[lb0], fmaf(w01, L[lb0 + 1],
                                   fmaf(w10, L[lb0 + WROW], w11 * L[lb0 + WROW + 1])));
                        float s1 = fmaf(w00, L[lb1], fmaf(w01, L[lb1 + 1],
                                   fmaf(w10, L[lb1 + WROW], w11 * L[lb1 + WROW + 1])));
                        unsigned int s2 = packh2(s0, s1);
                        GEMV8(tpL + cp * 8, s2);
                    }
                }
            } else {
                // slow path (rare, |offset| >= ~3): exact global reads, clamped
                int cy0 = min(max(iy0, 0), IMG - 1), cy1 = min(max(iy1, 0), IMG - 1);
                int cx0 = min(max(ix0, 0), IMG - 1), cx1 = min(max(ix1, 0), IMG - 1);
                int g00 = cy0 * IMG + cx0, g01 = cy0 * IMG + cx1;
                int g10 = cy1 * IMG + cx0, g11 = cy1 * IMG + cx1;
                const uint4* tpL = (const uint4*)(tw_h +
                    (unsigned)((r * 9 + k) * (CIN / 2) + cb * (CB2 / 2)) * COUT);
                for (int cp = 0; cp < CB2 / 2; ++cp) {
                    const float* xc0 = x + (cb * CB2 + 2 * cp) * HW;
                    const float* xc1 = xc0 + HW;
                    float s0 = fmaf(w00, xc0[g00], fmaf(w01, xc0[g01],
                               fmaf(w10, xc0[g10], w11 * xc0[g11])));
                    float s1 = fmaf(w00, xc1[g00], fmaf(w01, xc1[g01],
                               fmaf(w10, xc1[g10], w11 * xc1[g11])));
                    unsigned int s2 = packh2(s0, s1);
                    GEMV8(tpL + cp * 8, s2);
                }
            }
        }
    }

#pragma unroll
    for (int o = 0; o < 32; ++o) out[o * HW + p] = fmaxf(oacc[o], 0.0f);
}

extern "C" void kernel_launch(void* const* d_in, const int* in_sizes, int n_in,
                              void* d_out, int out_size, void* d_ws, size_t ws_size,
                              hipStream_t stream) {
    const float* x      = (const float*)d_in[0];
    const float* weight = (const float*)d_in[1];
    const float* offw   = (const float*)d_in[2];
    const float* offb   = (const float*)d_in[3];
    const float* mskw   = (const float*)d_in[4];
    const float* mskb   = (const float*)d_in[5];
    const float* gm     = (const float*)d_in[6];
    float* out = (float*)d_out;

    unsigned int* tw_h = (unsigned int*)d_ws;                   // 147456 B
    unsigned int* owm  = (unsigned int*)((char*)d_ws + 147456); // 432*9*4 = 15552 B
    float* om = (float*)((char*)d_ws + 294912);                 // 27*HW*4 = 28.3 MB

    build_tw_kernel<<<2, 256, 0, stream>>>(weight, tw_h);
    pack_owm_kernel<<<2, 256, 0, stream>>>(offw, mskw, owm);

    const int tiles = (IMG / TS) * (IMG / TS); // 1024
    offset_mask_kernel<<<tiles, 256, 0, stream>>>(x, owm, offb, mskb, om);
    deform_gemv_kernel<<<tiles, 256, 0, stream>>>(x, om, gm, tw_h, out);
}